// Round 1
// baseline (1206.198 us; speedup 1.0000x reference)
//
#include <hip/hip_runtime.h>
#include <math.h>

// Volume dims (1,1,160,192,160) fp32
#define DD 160
#define HHH 192
#define WWW 160
constexpr int HW = HHH * WWW;          // 30720
constexpr int NV = DD * HHH * WWW;     // 4915200
constexpr int CHUNK = 32;              // D-chunk per hd_cc thread; 160/32 = 5 chunks

__device__ __forceinline__ float ld3(const float* __restrict__ p, int d, int h, int w) {
    if ((unsigned)d >= (unsigned)DD || (unsigned)h >= (unsigned)HHH || (unsigned)w >= (unsigned)WWW)
        return 0.0f;
    return p[(d * HHH + h) * WWW + w];
}

__global__ void zero_acc(double* __restrict__ acc) {
    if (threadIdx.x < 3) acc[threadIdx.x] = 0.0;
}

// Laplacian 3x3x3, zero padded: 6*center - 6 face neighbors (symmetric => flip irrelevant)
__global__ void lap_pair(const float* __restrict__ a, const float* __restrict__ b,
                         float* __restrict__ oa, float* __restrict__ ob) {
    int i = blockIdx.x * 256 + threadIdx.x;
    if (i >= NV) return;
    int w = i % WWW;
    int h = (i / WWW) % HHH;
    int d = i / HW;
    float ra = 6.0f * a[i];
    float rb = 6.0f * b[i];
    ra -= ld3(a, d - 1, h, w) + ld3(a, d + 1, h, w) + ld3(a, d, h - 1, w) +
          ld3(a, d, h + 1, w) + ld3(a, d, h, w - 1) + ld3(a, d, h, w + 1);
    rb -= ld3(b, d - 1, h, w) + ld3(b, d + 1, h, w) + ld3(b, d, h - 1, w) +
          ld3(b, d, h + 1, w) + ld3(b, d, h, w - 1) + ld3(b, d, h, w + 1);
    oa[i] = ra;
    ob[i] = rb;
}

// Sobel magnitude sqrt(gx^2+gy^2+gz^2). Separable weights per reference kernels.
// gx: wgt = smooth_h[kh]*grad_w[kw] (const along d)
// gy: wgt = grad_d[kd]*smooth_w[kw] (const along h)
// gz: wgt = smooth_d[kd]*grad_h[kh] (const along w)
// (sign/flip convention irrelevant: components are squared)
__global__ void sobel_pair(const float* __restrict__ a, const float* __restrict__ b,
                           float* __restrict__ oa, float* __restrict__ ob) {
    int i = blockIdx.x * 256 + threadIdx.x;
    if (i >= NV) return;
    int w = i % WWW;
    int h = (i / WWW) % HHH;
    int d = i / HW;
    const float SM[3] = {1.0f, 2.0f, 1.0f};
    const float GR[3] = {-1.0f, 0.0f, 1.0f};
    float gxa = 0, gya = 0, gza = 0, gxb = 0, gyb = 0, gzb = 0;
#pragma unroll
    for (int kd = -1; kd <= 1; kd++) {
#pragma unroll
        for (int kh = -1; kh <= 1; kh++) {
#pragma unroll
            for (int kw = -1; kw <= 1; kw++) {
                float wx = SM[kh + 1] * GR[kw + 1];
                float wy = GR[kd + 1] * SM[kw + 1];
                float wz = SM[kd + 1] * GR[kh + 1];
                float va = ld3(a, d + kd, h + kh, w + kw);
                float vb = ld3(b, d + kd, h + kh, w + kw);
                gxa += wx * va; gya += wy * va; gza += wz * va;
                gxb += wx * vb; gyb += wy * vb; gzb += wz * vb;
            }
        }
    }
    oa[i] = sqrtf(gxa * gxa + gya * gya + gza * gza);
    ob[i] = sqrtf(gxb * gxb + gyb * gyb + gzb * gzb);
}

// Pass along W: 9-tap zero-padded sums of I, J, I^2, J^2, I*J
__global__ void wsum5(const float* __restrict__ a, const float* __restrict__ b,
                      float* __restrict__ s0, float* __restrict__ s1,
                      float* __restrict__ s2, float* __restrict__ s3,
                      float* __restrict__ s4) {
    int i = blockIdx.x * 256 + threadIdx.x;
    if (i >= NV) return;
    int w = i % WWW;
    int base = i - w;  // start of the W-line
    float sI = 0, sJ = 0, sI2 = 0, sJ2 = 0, sIJ = 0;
#pragma unroll
    for (int t = -4; t <= 4; t++) {
        int ww = w + t;
        if ((unsigned)ww < (unsigned)WWW) {
            float x = a[base + ww];
            float y = b[base + ww];
            sI += x; sJ += y; sI2 += x * x; sJ2 += y * y; sIJ += x * y;
        }
    }
    s0[i] = sI; s1[i] = sJ; s2[i] = sI2; s3[i] = sJ2; s4[i] = sIJ;
}

// Fused H-pass + D-pass + cc + reduction.
// One thread per (w,h,chunk): marches 32 output depths, 9-slice register ring.
__global__ void hd_cc(const float* __restrict__ s0, const float* __restrict__ s1,
                      const float* __restrict__ s2, const float* __restrict__ s3,
                      const float* __restrict__ s4, double* __restrict__ acc, int pair) {
    int t = blockIdx.x * 256 + threadIdx.x;
    int w = t % WWW;
    int h = (t / WWW) % HHH;
    int c = t / HW;           // chunk id 0..4
    int d0 = c * CHUNK;

    float ring[5][9];
#pragma unroll
    for (int q = 0; q < 5; q++)
#pragma unroll
        for (int j = 0; j < 9; j++) ring[q][j] = 0.0f;

    float local = 0.0f;

    // slices s = d0-4 .. d0+35; after pushing slice s, ring holds s-8..s
    // output depth d = s-4 once d >= d0
    for (int s = d0 - 4; s <= d0 + CHUNK + 3; s++) {
        float hs0 = 0, hs1 = 0, hs2 = 0, hs3 = 0, hs4 = 0;
        if (s >= 0 && s < DD) {
#pragma unroll
            for (int dh = -4; dh <= 4; dh++) {
                int hh = h + dh;
                if ((unsigned)hh < (unsigned)HHH) {
                    int idx = (s * HHH + hh) * WWW + w;
                    hs0 += s0[idx]; hs1 += s1[idx]; hs2 += s2[idx];
                    hs3 += s3[idx]; hs4 += s4[idx];
                }
            }
        }
        // shift register ring (constant indices -> stays in VGPRs)
#pragma unroll
        for (int q = 0; q < 5; q++) {
#pragma unroll
            for (int j = 0; j < 8; j++) ring[q][j] = ring[q][j + 1];
        }
        ring[0][8] = hs0; ring[1][8] = hs1; ring[2][8] = hs2;
        ring[3][8] = hs3; ring[4][8] = hs4;

        int d = s - 4;
        if (d >= d0) {
            float S[5];
#pragma unroll
            for (int q = 0; q < 5; q++) {
                float sum = 0.0f;
#pragma unroll
                for (int j = 0; j < 9; j++) sum += ring[q][j];
                S[q] = sum;
            }
            const float wsz = 729.0f;
            const float inv = 1.0f / 729.0f;
            float uI = S[0] * inv;
            float uJ = S[1] * inv;
            float cross = S[4] - uJ * S[0] - uI * S[1] + uI * uJ * wsz;
            float Iv = S[2] - 2.0f * uI * S[0] + uI * uI * wsz;
            float Jv = S[3] - 2.0f * uJ * S[1] + uJ * uJ * wsz;
            local += cross * cross / (Iv * Jv + 1e-5f);
        }
    }

    // wave reduce (64 lanes) then block reduce, one double atomic per block
    for (int off = 32; off > 0; off >>= 1) local += __shfl_down(local, off);
    __shared__ float wsum_[4];
    if ((threadIdx.x & 63) == 0) wsum_[threadIdx.x >> 6] = local;
    __syncthreads();
    if (threadIdx.x == 0) {
        float s = wsum_[0] + wsum_[1] + wsum_[2] + wsum_[3];
        atomicAdd(&acc[pair], (double)s);
    }
}

__global__ void finalize_k(const double* __restrict__ acc, float* __restrict__ out) {
    if (threadIdx.x == 0) {
        double v = 0.8 * acc[0] + 0.1 * acc[1] + 0.1 * acc[2];
        out[0] = (float)(-v / (double)NV);
    }
}

extern "C" void kernel_launch(void* const* d_in, const int* in_sizes, int n_in,
                              void* d_out, int out_size, void* d_ws, size_t ws_size,
                              hipStream_t stream) {
    const float* yt = (const float*)d_in[0];
    const float* yp = (const float*)d_in[1];
    float* out = (float*)d_out;

    // ws layout: [3 doubles acc | pad to 256B | bufA | bufB | s0..s4], 7*NV floats ~ 137.6 MB
    double* acc = (double*)d_ws;
    float* base = (float*)((char*)d_ws + 256);
    float* bufA = base;
    float* bufB = base + (size_t)NV;
    float* s0 = base + 2 * (size_t)NV;
    float* s1 = base + 3 * (size_t)NV;
    float* s2 = base + 4 * (size_t)NV;
    float* s3 = base + 5 * (size_t)NV;
    float* s4 = base + 6 * (size_t)NV;

    dim3 blk(256);
    dim3 grd(NV / 256);                              // 19200, exact
    dim3 grd2((WWW * HHH * (DD / CHUNK)) / 256);     // 600, exact

    hipLaunchKernelGGL(zero_acc, dim3(1), dim3(64), 0, stream, acc);

    // pair 0: raw inputs
    hipLaunchKernelGGL(wsum5, grd, blk, 0, stream, yt, yp, s0, s1, s2, s3, s4);
    hipLaunchKernelGGL(hd_cc, grd2, blk, 0, stream, s0, s1, s2, s3, s4, acc, 0);

    // pair 1: Laplacian
    hipLaunchKernelGGL(lap_pair, grd, blk, 0, stream, yt, yp, bufA, bufB);
    hipLaunchKernelGGL(wsum5, grd, blk, 0, stream, bufA, bufB, s0, s1, s2, s3, s4);
    hipLaunchKernelGGL(hd_cc, grd2, blk, 0, stream, s0, s1, s2, s3, s4, acc, 1);

    // pair 2: Sobel magnitude
    hipLaunchKernelGGL(sobel_pair, grd, blk, 0, stream, yt, yp, bufA, bufB);
    hipLaunchKernelGGL(wsum5, grd, blk, 0, stream, bufA, bufB, s0, s1, s2, s3, s4);
    hipLaunchKernelGGL(hd_cc, grd2, blk, 0, stream, s0, s1, s2, s3, s4, acc, 2);

    hipLaunchKernelGGL(finalize_k, dim3(1), dim3(1), 0, stream, acc, out);
}

// Round 2
// 527.945 us; speedup vs baseline: 2.2847x; 2.2847x over previous
//
#include <hip/hip_runtime.h>
#include <math.h>

// Volume dims (1,1,160,192,160) fp32
#define DD 160
#define HHH 192
#define WWW 160
constexpr int HW = HHH * WWW;          // 30720
constexpr int NV = DD * HHH * WWW;     // 4915200
constexpr int HC = 12;                 // H-chunk in whsum5: 192/12 = 16 chunks
constexpr int DC = 10;                 // D-chunk in dcc:    160/10 = 16 chunks

__device__ __forceinline__ float ld3(const float* __restrict__ p, int d, int h, int w) {
    if ((unsigned)d >= (unsigned)DD || (unsigned)h >= (unsigned)HHH || (unsigned)w >= (unsigned)WWW)
        return 0.0f;
    return p[(d * HHH + h) * WWW + w];
}

__global__ void zero_acc(double* __restrict__ acc) {
    if (threadIdx.x < 3) acc[threadIdx.x] = 0.0;
}

// Laplacian 3x3x3, zero padded: 6*center - 6 face neighbors (symmetric => flip irrelevant)
__global__ void lap_pair(const float* __restrict__ a, const float* __restrict__ b,
                         float* __restrict__ oa, float* __restrict__ ob) {
    int i = blockIdx.x * 256 + threadIdx.x;
    if (i >= NV) return;
    int w = i % WWW;
    int h = (i / WWW) % HHH;
    int d = i / HW;
    float ra = 6.0f * a[i];
    float rb = 6.0f * b[i];
    ra -= ld3(a, d - 1, h, w) + ld3(a, d + 1, h, w) + ld3(a, d, h - 1, w) +
          ld3(a, d, h + 1, w) + ld3(a, d, h, w - 1) + ld3(a, d, h, w + 1);
    rb -= ld3(b, d - 1, h, w) + ld3(b, d + 1, h, w) + ld3(b, d, h - 1, w) +
          ld3(b, d, h + 1, w) + ld3(b, d, h, w - 1) + ld3(b, d, h, w + 1);
    oa[i] = ra;
    ob[i] = rb;
}

// Sobel magnitude sqrt(gx^2+gy^2+gz^2); separable weights, sign irrelevant (squared).
__global__ void sobel_pair(const float* __restrict__ a, const float* __restrict__ b,
                           float* __restrict__ oa, float* __restrict__ ob) {
    int i = blockIdx.x * 256 + threadIdx.x;
    if (i >= NV) return;
    int w = i % WWW;
    int h = (i / WWW) % HHH;
    int d = i / HW;
    const float SM[3] = {1.0f, 2.0f, 1.0f};
    const float GR[3] = {-1.0f, 0.0f, 1.0f};
    float gxa = 0, gya = 0, gza = 0, gxb = 0, gyb = 0, gzb = 0;
#pragma unroll
    for (int kd = -1; kd <= 1; kd++) {
#pragma unroll
        for (int kh = -1; kh <= 1; kh++) {
#pragma unroll
            for (int kw = -1; kw <= 1; kw++) {
                float wx = SM[kh + 1] * GR[kw + 1];
                float wy = GR[kd + 1] * SM[kw + 1];
                float wz = SM[kd + 1] * GR[kh + 1];
                float va = ld3(a, d + kd, h + kh, w + kw);
                float vb = ld3(b, d + kd, h + kh, w + kw);
                gxa += wx * va; gya += wy * va; gza += wz * va;
                gxb += wx * vb; gyb += wy * vb; gzb += wz * vb;
            }
        }
    }
    oa[i] = sqrtf(gxa * gxa + gya * gya + gza * gza);
    ob[i] = sqrtf(gxb * gxb + gyb * gyb + gzb * gzb);
}

// Fused W-pass + H-pass: thread owns (d,w), marches an H-chunk with a 9-row
// register ring. Each step computes the incoming row's five W-sums on the fly.
__global__ void whsum5(const float* __restrict__ a, const float* __restrict__ b,
                       float* __restrict__ t0, float* __restrict__ t1,
                       float* __restrict__ t2, float* __restrict__ t3,
                       float* __restrict__ t4) {
    int t = blockIdx.x * 256 + threadIdx.x;
    int w = t % WWW;
    int d = (t / WWW) % DD;
    int c = t / (WWW * DD);
    int h0 = c * HC;

    float ring[5][9];
#pragma unroll
    for (int q = 0; q < 5; q++)
#pragma unroll
        for (int j = 0; j < 9; j++) ring[q][j] = 0.0f;

    for (int r = h0 - 4; r <= h0 + HC + 3; r++) {
        float q0 = 0, q1 = 0, q2 = 0, q3 = 0, q4 = 0;
        if ((unsigned)r < (unsigned)HHH) {
            int base = (d * HHH + r) * WWW;
#pragma unroll
            for (int ti = -4; ti <= 4; ti++) {
                int ww = w + ti;
                if ((unsigned)ww < (unsigned)WWW) {
                    float x = a[base + ww];
                    float y = b[base + ww];
                    q0 += x; q1 += y; q2 += x * x; q3 += y * y; q4 += x * y;
                }
            }
        }
#pragma unroll
        for (int q = 0; q < 5; q++)
#pragma unroll
            for (int j = 0; j < 8; j++) ring[q][j] = ring[q][j + 1];
        ring[0][8] = q0; ring[1][8] = q1; ring[2][8] = q2;
        ring[3][8] = q3; ring[4][8] = q4;

        int h = r - 4;
        if (h >= h0) {
            int idx = (d * HHH + h) * WWW + w;
            float S[5];
#pragma unroll
            for (int q = 0; q < 5; q++) {
                float s = 0.0f;
#pragma unroll
                for (int j = 0; j < 9; j++) s += ring[q][j];
                S[q] = s;
            }
            t0[idx] = S[0]; t1[idx] = S[1]; t2[idx] = S[2];
            t3[idx] = S[3]; t4[idx] = S[4];
        }
    }
}

// D-pass + cc + reduction: thread owns (w,h), marches a D-chunk with a
// 9-slice register ring; 5 coalesced loads per step.
__global__ void dcc(const float* __restrict__ t0, const float* __restrict__ t1,
                    const float* __restrict__ t2, const float* __restrict__ t3,
                    const float* __restrict__ t4, double* __restrict__ acc, int pair) {
    int t = blockIdx.x * 256 + threadIdx.x;
    int w = t % WWW;
    int h = (t / WWW) % HHH;
    int c = t / HW;
    int d0 = c * DC;

    float ring[5][9];
#pragma unroll
    for (int q = 0; q < 5; q++)
#pragma unroll
        for (int j = 0; j < 9; j++) ring[q][j] = 0.0f;

    float local = 0.0f;

    for (int s = d0 - 4; s <= d0 + DC + 3; s++) {
        float q0 = 0, q1 = 0, q2 = 0, q3 = 0, q4 = 0;
        if ((unsigned)s < (unsigned)DD) {
            int idx = (s * HHH + h) * WWW + w;
            q0 = t0[idx]; q1 = t1[idx]; q2 = t2[idx];
            q3 = t3[idx]; q4 = t4[idx];
        }
#pragma unroll
        for (int q = 0; q < 5; q++)
#pragma unroll
            for (int j = 0; j < 8; j++) ring[q][j] = ring[q][j + 1];
        ring[0][8] = q0; ring[1][8] = q1; ring[2][8] = q2;
        ring[3][8] = q3; ring[4][8] = q4;

        int d = s - 4;
        if (d >= d0) {
            float S[5];
#pragma unroll
            for (int q = 0; q < 5; q++) {
                float sum = 0.0f;
#pragma unroll
                for (int j = 0; j < 9; j++) sum += ring[q][j];
                S[q] = sum;
            }
            const float wsz = 729.0f;
            const float inv = 1.0f / 729.0f;
            float uI = S[0] * inv;
            float uJ = S[1] * inv;
            float cross = S[4] - uJ * S[0] - uI * S[1] + uI * uJ * wsz;
            float Iv = S[2] - 2.0f * uI * S[0] + uI * uI * wsz;
            float Jv = S[3] - 2.0f * uJ * S[1] + uJ * uJ * wsz;
            local += cross * cross / (Iv * Jv + 1e-5f);
        }
    }

    for (int off = 32; off > 0; off >>= 1) local += __shfl_down(local, off);
    __shared__ float wsum_[4];
    if ((threadIdx.x & 63) == 0) wsum_[threadIdx.x >> 6] = local;
    __syncthreads();
    if (threadIdx.x == 0) {
        float s = wsum_[0] + wsum_[1] + wsum_[2] + wsum_[3];
        atomicAdd(&acc[pair], (double)s);
    }
}

__global__ void finalize_k(const double* __restrict__ acc, float* __restrict__ out) {
    if (threadIdx.x == 0) {
        double v = 0.8 * acc[0] + 0.1 * acc[1] + 0.1 * acc[2];
        out[0] = (float)(-v / (double)NV);
    }
}

extern "C" void kernel_launch(void* const* d_in, const int* in_sizes, int n_in,
                              void* d_out, int out_size, void* d_ws, size_t ws_size,
                              hipStream_t stream) {
    const float* yt = (const float*)d_in[0];
    const float* yp = (const float*)d_in[1];
    float* out = (float*)d_out;

    // ws layout: [3 doubles acc | pad 256B | bufA | bufB | t0..t4] = 7*NV floats
    double* acc = (double*)d_ws;
    float* base = (float*)((char*)d_ws + 256);
    float* bufA = base;
    float* bufB = base + (size_t)NV;
    float* t0 = base + 2 * (size_t)NV;
    float* t1 = base + 3 * (size_t)NV;
    float* t2 = base + 4 * (size_t)NV;
    float* t3 = base + 5 * (size_t)NV;
    float* t4 = base + 6 * (size_t)NV;

    dim3 blk(256);
    dim3 grd(NV / 256);                                   // 19200 (stencils)
    dim3 grdWH((WWW * DD * (HHH / HC)) / 256);            // 1600
    dim3 grdD((WWW * HHH * (DD / DC)) / 256);             // 1920

    hipLaunchKernelGGL(zero_acc, dim3(1), dim3(64), 0, stream, acc);

    // pair 0: raw inputs
    hipLaunchKernelGGL(whsum5, grdWH, blk, 0, stream, yt, yp, t0, t1, t2, t3, t4);
    hipLaunchKernelGGL(dcc, grdD, blk, 0, stream, t0, t1, t2, t3, t4, acc, 0);

    // pair 1: Laplacian
    hipLaunchKernelGGL(lap_pair, grd, blk, 0, stream, yt, yp, bufA, bufB);
    hipLaunchKernelGGL(whsum5, grdWH, blk, 0, stream, bufA, bufB, t0, t1, t2, t3, t4);
    hipLaunchKernelGGL(dcc, grdD, blk, 0, stream, t0, t1, t2, t3, t4, acc, 1);

    // pair 2: Sobel magnitude
    hipLaunchKernelGGL(sobel_pair, grd, blk, 0, stream, yt, yp, bufA, bufB);
    hipLaunchKernelGGL(whsum5, grdWH, blk, 0, stream, bufA, bufB, t0, t1, t2, t3, t4);
    hipLaunchKernelGGL(dcc, grdD, blk, 0, stream, t0, t1, t2, t3, t4, acc, 2);

    hipLaunchKernelGGL(finalize_k, dim3(1), dim3(1), 0, stream, acc, out);
}